// Round 12
// baseline (435.040 us; speedup 1.0000x reference)
//
#include <hip/hip_runtime.h>
#include <hip/hip_fp16.h>

#define N_NODES 200000
#define N_EDGES 6400000
#define N_GRAPHS 512
#define HALFN 100000     // src-split boundary for layer2 passes

#define NB1 196      // coarse dst buckets: 1024 nodes each
#define CB 1024
#define CHUNK 4096
#define NCH 1563     // 1563*4096 = 6,402,048 >= 6.4M
#define NGRP 25
#define CPG 63       // 25*63 = 1575 >= 1563
#define BCAP 34816   // bucket edge capacity: mean 32,653 + 12 sigma (sigma~180)
#define NBLK32 (N_NODES / 32)

// ---------- non-temporal helpers ----------
typedef float vf4 __attribute__((ext_vector_type(4)));
typedef float vf2 __attribute__((ext_vector_type(2)));
typedef unsigned vu2 __attribute__((ext_vector_type(2)));

__device__ __forceinline__ unsigned ntload_u(const unsigned* p) {
  return __builtin_nontemporal_load(p);
}
__device__ __forceinline__ int ntload_i(const int* p) { return __builtin_nontemporal_load(p); }
__device__ __forceinline__ float ntload_f(const float* p) {
  return __builtin_nontemporal_load(p);
}
__device__ __forceinline__ void ntstore_u(unsigned* p, unsigned v) {
  __builtin_nontemporal_store(v, p);
}

// ---------- partition pass 1: counting sort of edges by dst>>10 (coarse) ----------
__global__ __launch_bounds__(256) void count_kernel(const int* __restrict__ dst,
                                                    unsigned short* __restrict__ H) {
  __shared__ unsigned hist[4][NB1];
  int t = threadIdx.x, w = t >> 6;
  for (int i = t; i < 4 * NB1; i += 256) ((unsigned*)hist)[i] = 0;
  __syncthreads();
  int c = blockIdx.x;
  long e0 = (long)c * CHUNK;
  long rem = (long)N_EDGES - e0;
  int n = rem > CHUNK ? CHUNK : (int)rem;
  for (int i = t; i < n; i += 256) atomicAdd(&hist[w][dst[e0 + i] >> 10], 1u);
  __syncthreads();
  for (int b = t; b < NB1; b += 256)
    H[(size_t)c * NB1 + b] =
        (unsigned short)(hist[0][b] + hist[1][b] + hist[2][b] + hist[3][b]);
}

__global__ __launch_bounds__(256) void scan_bins1_kernel(unsigned short* __restrict__ H,
                                                         unsigned* __restrict__ P) {
  int b = blockIdx.x * 256 + threadIdx.x;
  int g = blockIdx.y;
  if (b >= NB1) return;
  int c0 = g * CPG, c1 = min(NCH, (g + 1) * CPG);
  unsigned run = 0;
  for (int c = c0; c < c1; c++) {
    unsigned t = H[(size_t)c * NB1 + b];
    H[(size_t)c * NB1 + b] = (unsigned short)run;
    run += t;
  }
  P[(size_t)g * NB1 + b] = run;
}

__global__ __launch_bounds__(256) void scan_bins2_kernel(unsigned* __restrict__ P,
                                                         unsigned* __restrict__ bucketTotal) {
  int b = blockIdx.x * 256 + threadIdx.x;
  if (b >= NB1) return;
  unsigned run = 0;
  for (int g = 0; g < NGRP; g++) {
    unsigned t = P[(size_t)g * NB1 + b];
    P[(size_t)g * NB1 + b] = run;
    run += t;
  }
  bucketTotal[b] = run;
}

__global__ __launch_bounds__(256) void scan_total_kernel(const unsigned* __restrict__ bucketTotal,
                                                         unsigned* __restrict__ bucketStart) {
  __shared__ unsigned partial[256];
  int t = threadIdx.x;
  unsigned v = (t < NB1) ? bucketTotal[t] : 0u;
  partial[t] = v;
  __syncthreads();
  for (int off = 1; off < 256; off <<= 1) {
    unsigned add = (t >= off) ? partial[t - off] : 0u;
    __syncthreads();
    partial[t] += add;
    __syncthreads();
  }
  if (t < NB1) bucketStart[t] = partial[t] - v;  // exclusive
  if (t == 0) bucketStart[NB1] = N_EDGES;
}

// scatterA: chunk-local LDS counting sort by coarse bucket, coalesced-run writes
// X1 entry = (src<<10)|(dst&1023)
__global__ __launch_bounds__(256) void scatterA_kernel(
    const int* __restrict__ src, const int* __restrict__ dst,
    const unsigned short* __restrict__ H, const unsigned* __restrict__ P,
    const unsigned* __restrict__ bucketStart, unsigned* __restrict__ X1) {
  __shared__ unsigned ssort[CHUNK];        // 16 KB (CHUNK=4096)
  __shared__ unsigned char sbort[CHUNK];   // 4 KB
  __shared__ unsigned histw[4][NB1];
  __shared__ unsigned curw[4][NB1];
  __shared__ unsigned gbase[NB1];
  __shared__ unsigned partial[256];
  int t = threadIdx.x, w = t >> 6;
  int c = blockIdx.x;
  int g = c / CPG;
  long e0 = (long)c * CHUNK;
  long rem = (long)N_EDGES - e0;
  int n = rem > CHUNK ? CHUNK : (int)rem;
  for (int i = t; i < 4 * NB1; i += 256) ((unsigned*)histw)[i] = 0;
  __syncthreads();
  for (int i = t; i < n; i += 256) atomicAdd(&histw[w][dst[e0 + i] >> 10], 1u);
  __syncthreads();
  unsigned tot = 0, h0 = 0, h1 = 0, h2 = 0, h3 = 0;
  if (t < NB1) {
    h0 = histw[0][t]; h1 = histw[1][t]; h2 = histw[2][t]; h3 = histw[3][t];
    tot = h0 + h1 + h2 + h3;
  }
  partial[t] = tot;
  __syncthreads();
  for (int off = 1; off < 256; off <<= 1) {
    unsigned add = (t >= off) ? partial[t - off] : 0u;
    __syncthreads();
    partial[t] += add;
    __syncthreads();
  }
  if (t < NB1) {
    unsigned ex = partial[t] - tot;
    unsigned r = ex;
    curw[0][t] = r; r += h0;
    curw[1][t] = r; r += h1;
    curw[2][t] = r; r += h2;
    curw[3][t] = r;
    gbase[t] = bucketStart[t] + P[(size_t)g * NB1 + t] + (unsigned)H[(size_t)c * NB1 + t] - ex;
  }
  __syncthreads();
  for (int i = t; i < n; i += 256) {
    int d = dst[e0 + i], s = src[e0 + i];
    int b = d >> 10;
    unsigned r = atomicAdd(&curw[w][b], 1u);
    ssort[r] = ((unsigned)s << 10) | (unsigned)(d & 1023);
    sbort[r] = (unsigned char)b;
  }
  __syncthreads();
  for (int j = t; j < n; j += 256) X1[gbase[sbort[j]] + j] = ssort[j];
}

// sortBC: MERGED scatterB+sort2. One block per 1024-node coarse bucket,
// 512 thr, 157.7KB LDS (136KB edge buf + 2048-bin hist/cur + scan scratch).
// Pass 1: histogram X1 by bin = (node_low10<<1)|(src>=HALFN). Scan. Pass 2:
// re-read X1 (L2-hot, 136KB/block) scattering into LDS buf; coalesced write
// packedB = buf>>10. packedB ALIASES X1: each block reads its entire range
// before writing it, ranges disjoint across blocks -> safe.
// Deletes scatterB's 51.2MB global r/w pass entirely.
__global__ __launch_bounds__(512) void sortBC_kernel(
    const unsigned* X1r, const unsigned* __restrict__ bucketStart,
    unsigned* packedB, unsigned* __restrict__ nodeStart,
    unsigned char* __restrict__ deltaSplit) {
  __shared__ unsigned buf[BCAP];       // 136 KB
  __shared__ unsigned hist[2048];      // 8 KB (becomes base in-place)
  __shared__ unsigned cur[2048];       // 8 KB
  __shared__ unsigned partial[512];    // 2 KB
  int t = threadIdx.x, b = blockIdx.x;
  unsigned cs0 = bucketStart[b], cs1 = bucketStart[b + 1];
  int n = (int)(cs1 - cs0);
  for (int i = t; i < 2048; i += 512) hist[i] = 0;
  __syncthreads();
  for (int i = t; i < n; i += 512) {
    unsigned v = ntload_u(&X1r[cs0 + i]);
    unsigned bin = ((v & 1023u) << 1) | ((v >> 10) >= HALFN ? 1u : 0u);
    atomicAdd(&hist[bin], 1u);
  }
  __syncthreads();
  // exclusive scan of 2048 bins: 4 bins/thread + Hillis-Steele over 512
  unsigned a0 = hist[4 * t], a1 = hist[4 * t + 1], a2 = hist[4 * t + 2], a3 = hist[4 * t + 3];
  unsigned sum = a0 + a1 + a2 + a3;
  partial[t] = sum;
  __syncthreads();
  for (int off = 1; off < 512; off <<= 1) {
    unsigned add = (t >= off) ? partial[t - off] : 0u;
    __syncthreads();
    partial[t] += add;
    __syncthreads();
  }
  unsigned run = partial[t] - sum;
  hist[4 * t] = run; cur[4 * t] = run; run += a0;
  hist[4 * t + 1] = run; cur[4 * t + 1] = run; run += a1;
  hist[4 * t + 2] = run; cur[4 * t + 2] = run; run += a2;
  hist[4 * t + 3] = run; cur[4 * t + 3] = run;
  __syncthreads();
  // nodeStart + deltaSplit (bucket 195: node 200000 writes the sentinel = cs1)
  for (int k = t; k < CB; k += 512) {
    int gn = b * CB + k;
    if (gn < N_NODES) {
      nodeStart[gn] = cs0 + hist[2 * k];
      deltaSplit[gn] = (unsigned char)(hist[2 * k + 1] - hist[2 * k]);
    } else if (gn == N_NODES) {
      nodeStart[gn] = cs0 + hist[2 * k];  // == cs1 == N_EDGES
    }
  }
  // pass 2: L2-hot re-read, scatter into LDS
  for (int i = t; i < n; i += 512) {
    unsigned v = X1r[cs0 + i];
    unsigned bin = ((v & 1023u) << 1) | ((v >> 10) >= HALFN ? 1u : 0u);
    unsigned pos = atomicAdd(&cur[bin], 1u);
    buf[pos] = v;
  }
  __syncthreads();
  for (int i = t; i < n; i += 512) ntstore_u(&packedB[cs0 + i], buf[i] >> 10);
}

// ---------- xpad (fp16, 8B records -> 1.6MB table) ----------
__global__ __launch_bounds__(256) void xpad_kernel(const float* __restrict__ x,
                                                   uint2* __restrict__ xph) {
  int n = blockIdx.x * 256 + threadIdx.x;
  if (n >= N_NODES) return;
  __half2 a = __floats2half2_rn(x[3 * n], x[3 * n + 1]);
  __half2 b = __floats2half2_rn(x[3 * n + 2], 0.f);
  xph[n] = make_uint2(*(unsigned*)&a, *(unsigned*)&b);
}

__device__ __forceinline__ void half8_unpack(uint4 g, float* f) {
  const __half2* h2 = reinterpret_cast<const __half2*>(&g);
#pragma unroll
  for (int j = 0; j < 4; j++) {
    float2 fj = __half22float2(h2[j]);
    f[2 * j] = fj.x;
    f[2 * j + 1] = fj.y;
  }
}

// ---------- layer 1a: gather-only, 8 thr/node, fp16 x-table (1.6MB) ----------
__global__ __launch_bounds__(256) void layer1a_kernel(
    const unsigned* __restrict__ packed, const unsigned* __restrict__ nodeStart,
    const uint2* __restrict__ xph, float* __restrict__ agg) {
  __shared__ float plds[256 * 9];
  int t = threadIdx.x, ln = t >> 3, p = t & 7;
  int node = blockIdx.x * 32 + ln;
  unsigned s1v = ntload_u(&nodeStart[node + 1]);
  float a0 = 0.f, a1 = 0.f, a2 = 0.f;
  for (unsigned base = ntload_u(&nodeStart[node]) + p; base < s1v; base += 32) {
    unsigned i1 = base + 8, i2 = base + 16, i3 = base + 24;
    unsigned e0 = ntload_u(&packed[base]);
    unsigned e1 = ntload_u(&packed[i1]);
    unsigned e2 = ntload_u(&packed[i2]);
    unsigned e3 = ntload_u(&packed[i3]);
    uint2 g0 = xph[e0], g1 = xph[e1], g2 = xph[e2], g3 = xph[e3];
    float m1 = (i1 < s1v) ? 1.f : 0.f;
    float m2 = (i2 < s1v) ? 1.f : 0.f;
    float m3 = (i3 < s1v) ? 1.f : 0.f;
    float2 xy0 = __half22float2(*(const __half2*)&g0.x);
    float2 zw0 = __half22float2(*(const __half2*)&g0.y);
    float2 xy1 = __half22float2(*(const __half2*)&g1.x);
    float2 zw1 = __half22float2(*(const __half2*)&g1.y);
    float2 xy2 = __half22float2(*(const __half2*)&g2.x);
    float2 zw2 = __half22float2(*(const __half2*)&g2.y);
    float2 xy3 = __half22float2(*(const __half2*)&g3.x);
    float2 zw3 = __half22float2(*(const __half2*)&g3.y);
    a0 += xy0.x + m1 * xy1.x + m2 * xy2.x + m3 * xy3.x;
    a1 += xy0.y + m1 * xy1.y + m2 * xy2.y + m3 * xy3.y;
    a2 += zw0.x + m1 * zw1.x + m2 * zw2.x + m3 * zw3.x;
  }
  plds[t * 9] = a0; plds[t * 9 + 1] = a1; plds[t * 9 + 2] = a2;
  __syncthreads();
  if (p < 4) {
    int q0 = ln * 72 + p;
    float v = 0.f;
    if (p < 3)
      v = plds[q0] + plds[q0 + 9] + plds[q0 + 18] + plds[q0 + 27] +
          plds[q0 + 36] + plds[q0 + 45] + plds[q0 + 54] + plds[q0 + 63];
    agg[(size_t)node * 4 + p] = v;
  }
}

// ---------- layer 1b: dense-only. Reads x + agg; writes t2h + r2h (fp16) ----------
__global__ __launch_bounds__(256) void layer1b_kernel(
    const float* __restrict__ x, const float4* __restrict__ agg,
    const float* __restrict__ W1_rel, const float* __restrict__ b1,
    const float* __restrict__ W1_root,
    const float* __restrict__ W2_rel, const float* __restrict__ W2_root,
    uint4* __restrict__ t2h4, uint4* __restrict__ r2h4) {
  __shared__ float sW1rel[96], sW1root[96], sb1[32], sW2rel[512], sW2root[512];
  for (int i = threadIdx.x; i < 96; i += 256) { sW1rel[i] = W1_rel[i]; sW1root[i] = W1_root[i]; }
  for (int i = threadIdx.x; i < 32; i += 256) sb1[i] = b1[i];
  for (int i = threadIdx.x; i < 512; i += 256) { sW2rel[i] = W2_rel[i]; sW2root[i] = W2_root[i]; }
  __syncthreads();
  int node = blockIdx.x * 256 + threadIdx.x;
  if (node >= N_NODES) return;
  float4 A = agg[node];
  float xv0 = x[3 * node], xv1 = x[3 * node + 1], xv2 = x[3 * node + 2];
  float h[32];
#pragma unroll
  for (int k = 0; k < 32; k++) {
    float v = sW1rel[3 * k] * A.x + sW1rel[3 * k + 1] * A.y + sW1rel[3 * k + 2] * A.z +
              sW1root[3 * k] * xv0 + sW1root[3 * k + 1] * xv1 + sW1root[3 * k + 2] * xv2 +
              sb1[k];
    h[k] = fmaxf(v, 0.f);
  }
  unsigned tp[8];
#pragma unroll
  for (int j = 0; j < 16; j += 2) {
    float t0 = 0.f, t1 = 0.f;
#pragma unroll
    for (int k = 0; k < 32; k++) {
      t0 += sW2rel[32 * j + k] * h[k];
      t1 += sW2rel[32 * (j + 1) + k] * h[k];
    }
    __half2 pk = __halves2half2(__float2half_rn(t0), __float2half_rn(t1));
    tp[j >> 1] = *(unsigned*)&pk;
  }
  t2h4[(size_t)node * 2] = make_uint4(tp[0], tp[1], tp[2], tp[3]);
  t2h4[(size_t)node * 2 + 1] = make_uint4(tp[4], tp[5], tp[6], tp[7]);
  unsigned rp[8];
#pragma unroll
  for (int j = 0; j < 16; j += 2) {
    float r0 = 0.f, r1 = 0.f;
#pragma unroll
    for (int k = 0; k < 32; k++) {
      r0 += sW2root[32 * j + k] * h[k];
      r1 += sW2root[32 * (j + 1) + k] * h[k];
    }
    __half2 pk = __halves2half2(__float2half_rn(r0), __float2half_rn(r1));
    rp[j >> 1] = *(unsigned*)&pk;
  }
  r2h4[(size_t)node * 2] = make_uint4(rp[0], rp[1], rp[2], rp[3]);
  r2h4[(size_t)node * 2 + 1] = make_uint4(rp[4], rp[5], rp[6], rp[7]);
}

// ---------- layer 2g: SRC-RANGE split passes (R9-proven) ----------
__global__ __launch_bounds__(256) void layer2g_kernel(
    const unsigned* __restrict__ packed, const unsigned* __restrict__ nodeStart,
    const unsigned char* __restrict__ deltaSplit,
    const uint4* __restrict__ t2h4, __half* __restrict__ agg2, int pass) {
  __shared__ float plds[256 * 17];
  int t = threadIdx.x, ln = t >> 3, p = t & 7;
  int node = blockIdx.x * 32 + ln;
  unsigned s0n = ntload_u(&nodeStart[node]);
  unsigned s1n = ntload_u(&nodeStart[node + 1]);
  unsigned split = s0n + (unsigned)deltaSplit[node];
  unsigned lo = pass ? split : s0n;
  unsigned hi = pass ? s1n : split;
  float acc[16];
#pragma unroll
  for (int j = 0; j < 16; j++) acc[j] = 0.f;
  for (unsigned base = lo + p; base < hi; base += 16) {
    unsigned i1 = base + 8;
    unsigned e0 = ntload_u(&packed[base]);
    unsigned e1r = ntload_u(&packed[i1]);
    bool in1 = i1 < hi;
    unsigned e1 = in1 ? e1r : e0;  // clamp masked slot to e0's (hot) line
    uint4 g0a = t2h4[(size_t)e0 * 2], g0b = t2h4[(size_t)e0 * 2 + 1];
    uint4 g1a = t2h4[(size_t)e1 * 2], g1b = t2h4[(size_t)e1 * 2 + 1];
    float f0[16], f1[16];
    half8_unpack(g0a, f0);
    half8_unpack(g0b, f0 + 8);
    half8_unpack(g1a, f1);
    half8_unpack(g1b, f1 + 8);
    float m1 = in1 ? 1.f : 0.f;
#pragma unroll
    for (int j = 0; j < 16; j++) acc[j] += f0[j] + m1 * f1[j];
  }
#pragma unroll
  for (int j = 0; j < 16; j++) plds[t * 17 + j] = acc[j];
  __syncthreads();
  int qb = ln * 8 * 17;
  float s0 = 0.f, s1 = 0.f;
#pragma unroll
  for (int k = 0; k < 8; k++) {
    s0 += plds[qb + k * 17 + 2 * p];
    s1 += plds[qb + k * 17 + 2 * p + 1];
  }
  __half* dst = &agg2[(size_t)node * 16 + 2 * p];
  if (pass) {
    __half2 old = *(const __half2*)dst;
    float2 of = __half22float2(old);
    s0 += of.x;
    s1 += of.y;
  }
  *(__half2*)dst = __halves2half2(__float2half_rn(s0), __float2half_rn(s1));
}

// ---------- layer 2e: dense epilogue, 1 thr/node. r3 IN-PLACE over agg2 ----------
__global__ __launch_bounds__(256) void layer2e_kernel(
    const uint4* agg2q, const uint4* __restrict__ r2h4,
    const float* __restrict__ b2, const float* __restrict__ W3_rel,
    const float* __restrict__ W3_root, uint4* __restrict__ t3h4, float4* r34) {
  __shared__ float sW3rel[128], sW3root[128], sb2[16];
  for (int i = threadIdx.x; i < 128; i += 256) { sW3rel[i] = W3_rel[i]; sW3root[i] = W3_root[i]; }
  if (threadIdx.x < 16) sb2[threadIdx.x] = b2[threadIdx.x];
  __syncthreads();
  int node = blockIdx.x * 256 + threadIdx.x;
  if (node >= N_NODES) return;
  uint4 ga = agg2q[(size_t)node * 2];
  uint4 gb = agg2q[(size_t)node * 2 + 1];
  float ag[16];
  half8_unpack(ga, ag);
  half8_unpack(gb, ag + 8);
  uint4 ra = r2h4[(size_t)node * 2];
  uint4 rb = r2h4[(size_t)node * 2 + 1];
  float rv2[16];
  half8_unpack(ra, rv2);
  half8_unpack(rb, rv2 + 8);
  float h[16];
#pragma unroll
  for (int k = 0; k < 16; k++) h[k] = fmaxf(ag[k] + rv2[k] + sb2[k], 0.f);
  unsigned tp[4];
#pragma unroll
  for (int j = 0; j < 8; j += 2) {
    float t0 = 0.f, t1 = 0.f;
#pragma unroll
    for (int k = 0; k < 16; k++) {
      t0 += sW3rel[16 * j + k] * h[k];
      t1 += sW3rel[16 * (j + 1) + k] * h[k];
    }
    __half2 pk = __halves2half2(__float2half_rn(t0), __float2half_rn(t1));
    tp[j >> 1] = *(unsigned*)&pk;
  }
  t3h4[node] = make_uint4(tp[0], tp[1], tp[2], tp[3]);
  float rv[8];
#pragma unroll
  for (int j = 0; j < 8; j++) {
    float a = 0.f;
#pragma unroll
    for (int k = 0; k < 16; k++) a += sW3root[16 * j + k] * h[k];
    rv[j] = a;
  }
  r34[(size_t)node * 2] = make_float4(rv[0], rv[1], rv[2], rv[3]);
  r34[(size_t)node * 2 + 1] = make_float4(rv[4], rv[5], rv[6], rv[7]);
}

// ---------- layer 3: 8 thr/node + block-level segmented-max before atomicMax ----------
__global__ __launch_bounds__(256) void layer3_kernel(
    const unsigned* __restrict__ packed, const unsigned* __restrict__ nodeStart,
    const uint4* __restrict__ t3h4, const float* __restrict__ r3,
    const float* __restrict__ b3,
    const int* __restrict__ batch, unsigned* __restrict__ pooled) {
  __shared__ float plds[256 * 9];
  __shared__ float sb3[8];
  __shared__ int sgid[32];
  if (threadIdx.x < 8) sb3[threadIdx.x] = b3[threadIdx.x];
  __syncthreads();
  int t = threadIdx.x, ln = t >> 3, p = t & 7;
  int node = blockIdx.x * 32 + ln;
  unsigned s1v = ntload_u(&nodeStart[node + 1]);
  float acc[8];
#pragma unroll
  for (int j = 0; j < 8; j++) acc[j] = 0.f;
  for (unsigned base = ntload_u(&nodeStart[node]) + p; base < s1v; base += 32) {
    unsigned i1 = base + 8, i2 = base + 16, i3 = base + 24;
    unsigned e0 = ntload_u(&packed[base]);
    unsigned e1 = ntload_u(&packed[i1]);
    unsigned e2 = ntload_u(&packed[i2]);
    unsigned e3 = ntload_u(&packed[i3]);
    uint4 g0 = t3h4[e0];
    uint4 g1 = t3h4[e1];
    uint4 g2 = t3h4[e2];
    uint4 g3 = t3h4[e3];
    float m1 = (i1 < s1v) ? 1.f : 0.f;
    float m2 = (i2 < s1v) ? 1.f : 0.f;
    float m3 = (i3 < s1v) ? 1.f : 0.f;
    float f0[8], f1[8], f2[8], f3[8];
    half8_unpack(g0, f0);
    half8_unpack(g1, f1);
    half8_unpack(g2, f2);
    half8_unpack(g3, f3);
#pragma unroll
    for (int j = 0; j < 8; j++)
      acc[j] += f0[j] + m1 * f1[j] + m2 * f2[j] + m3 * f3[j];
  }
#pragma unroll
  for (int j = 0; j < 8; j++) plds[t * 9 + j] = acc[j];
  __syncthreads();
  int gg = ntload_i(&batch[node]);
  int q0 = ln * 72 + p;
  float v = plds[q0] + plds[q0 + 9] + plds[q0 + 18] + plds[q0 + 27] +
            plds[q0 + 36] + plds[q0 + 45] + plds[q0 + 54] + plds[q0 + 63];
  float h = fmaxf(v + sb3[p] + ntload_f(&r3[(size_t)node * 8 + p]), 0.f);
  __syncthreads();
  plds[ln * 9 + p] = h;
  if (p == 0) sgid[ln] = gg;
  __syncthreads();
  if (t < 8) {
    int gcur = sgid[0];
    float m = plds[t];
    for (int l = 1; l < 32; l++) {
      int g2 = sgid[l];
      float hv = plds[l * 9 + t];
      if (g2 != gcur) {
        atomicMax(&pooled[8 * gcur + t], __float_as_uint(m));
        gcur = g2;
        m = hv;
      } else {
        m = fmaxf(m, hv);
      }
    }
    atomicMax(&pooled[8 * gcur + t], __float_as_uint(m));
  }
}

__global__ __launch_bounds__(256) void final_kernel(
    const unsigned* __restrict__ pooled, const float* __restrict__ W_lin,
    const float* __restrict__ b_lin, float* __restrict__ out) {
  int g = blockIdx.x * blockDim.x + threadIdx.x;
  if (g >= N_GRAPHS) return;
  float acc = b_lin[0];
#pragma unroll
  for (int f = 0; f < 8; f++) acc += __uint_as_float(pooled[8 * g + f]) * W_lin[f];
  out[g] = acc;
}

extern "C" void kernel_launch(void* const* d_in, const int* in_sizes, int n_in,
                              void* d_out, int out_size, void* d_ws, size_t ws_size,
                              hipStream_t stream) {
  const float* x = (const float*)d_in[0];
  const int* ei = (const int*)d_in[1];
  const int* src = ei;
  const int* dst = ei + N_EDGES;
  const int* batch = (const int*)d_in[2];
  const float* W1_rel = (const float*)d_in[3];
  const float* b1 = (const float*)d_in[4];
  const float* W1_root = (const float*)d_in[5];
  const float* W2_rel = (const float*)d_in[6];
  const float* b2 = (const float*)d_in[7];
  const float* W2_root = (const float*)d_in[8];
  const float* W3_rel = (const float*)d_in[9];
  const float* b3 = (const float*)d_in[10];
  const float* W3_root = (const float*)d_in[11];
  const float* W_lin = (const float*)d_in[12];
  const float* b_lin = (const float*)d_in[13];
  float* out = (float*)d_out;

  // ---- workspace layout (bytes) ----
  // R_A (0..25.6M): free during partition (X2 eliminated). Post-partition:
  //   r2h  0..6.4M       (layer1b w / layer2e r)
  //   agg2 6.4..12.8M    (layer2g w/r) -> r3 fp32 in-place (layer2e w, layer3 r)
  //   t3h  12.8..16.0M   (layer2e w, layer3 r)
  //   t2h  16.0..22.4M   (layer1b w, layer2g r)
  // R_B (25.6..51.2M): X1 (scatterA out) -> packedB IN-PLACE (sortBC) + 128 pad
  // meta (51.2M+128..): H(612K)/P/totals/bucketStart (ends ~51.84M),
  //   agg   52.0..55.2M  (layer1a w, layer1b r)
  //   xpadh 55.3..56.9M  (xpad w FIRST, layer1a r)
  // pooled 57.6M; deltaSplit (uchar) 57.616M; nodeStart 57.954M -> 58.754M
  char* ws = (char*)d_ws;
  uint4* r2h = (uint4*)(ws + 0);
  __half* agg2 = (__half*)(ws + 6400000);
  float* r3 = (float*)(ws + 6400000);
  unsigned* t3h = (unsigned*)(ws + 12800000);
  unsigned* t2h = (unsigned*)(ws + 16000000);
  unsigned* X1 = (unsigned*)(ws + 25600000);
  unsigned* packedB = (unsigned*)(ws + 25600000);  // in-place over X1 (sortBC)
  unsigned short* H = (unsigned short*)(ws + 51200128);
  unsigned* P = (unsigned*)(ws + 51812824);
  unsigned* bucketTotal = (unsigned*)(ws + 51832424);
  unsigned* bucketStart = (unsigned*)(ws + 51833208);
  float* agg = (float*)(ws + 52000000);
  uint2* xpadh = (uint2*)(ws + 55300000);
  unsigned* pooled = (unsigned*)(ws + 57600128);
  unsigned char* deltaSplit = (unsigned char*)(ws + 57616512);
  unsigned* nodeStart = (unsigned*)(ws + 57954016);

  hipMemsetAsync(pooled, 0, N_GRAPHS * 8 * sizeof(unsigned), stream);
  hipMemsetAsync(packedB + N_EDGES, 0, 128, stream);  // batch overrun pad (src=0 safe)

  // xpadh first: independent of partition, needed by layer1a
  xpad_kernel<<<(N_NODES + 255) / 256, 256, 0, stream>>>(x, xpadh);

  // partition: coarse sort (196 buckets) -> merged in-LDS node sort (sortBC)
  count_kernel<<<NCH, 256, 0, stream>>>(dst, H);
  scan_bins1_kernel<<<dim3((NB1 + 255) / 256, NGRP), 256, 0, stream>>>(H, P);
  scan_bins2_kernel<<<(NB1 + 255) / 256, 256, 0, stream>>>(P, bucketTotal);
  scan_total_kernel<<<1, 256, 0, stream>>>(bucketTotal, bucketStart);
  scatterA_kernel<<<NCH, 256, 0, stream>>>(src, dst, H, P, bucketStart, X1);
  sortBC_kernel<<<NB1, 512, 0, stream>>>(X1, bucketStart, packedB, nodeStart, deltaSplit);

  // layer1: gather (fp16 table) + dense epilogue
  layer1a_kernel<<<NBLK32, 256, 0, stream>>>(packedB, nodeStart, xpadh, agg);
  layer1b_kernel<<<(N_NODES + 255) / 256, 256, 0, stream>>>(
      x, (const float4*)agg, W1_rel, b1, W1_root, W2_rel, W2_root,
      (uint4*)t2h, r2h);

  // layer2: two src-range passes + dense epilogue
  layer2g_kernel<<<NBLK32, 256, 0, stream>>>(packedB, nodeStart, deltaSplit,
                                             (const uint4*)t2h, agg2, 0);
  layer2g_kernel<<<NBLK32, 256, 0, stream>>>(packedB, nodeStart, deltaSplit,
                                             (const uint4*)t2h, agg2, 1);
  layer2e_kernel<<<(N_NODES + 255) / 256, 256, 0, stream>>>(
      (const uint4*)agg2, (const uint4*)r2h, b2, W3_rel, W3_root,
      (uint4*)t3h, (float4*)r3);

  layer3_kernel<<<NBLK32, 256, 0, stream>>>(packedB, nodeStart, (const uint4*)t3h, r3, b3,
                                            batch, pooled);
  final_kernel<<<(N_GRAPHS + 255) / 256, 256, 0, stream>>>(pooled, W_lin, b_lin, out);
}

// Round 13
// 416.276 us; speedup vs baseline: 1.0451x; 1.0451x over previous
//
#include <hip/hip_runtime.h>
#include <hip/hip_fp16.h>

#define N_NODES 200000
#define N_EDGES 6400000
#define N_GRAPHS 512
#define HALFN 100000     // src-split boundary for layer2 passes

#define NB1 196      // coarse dst buckets: 1024 nodes each
#define CB 1024
#define NSB 16       // sub-buckets per coarse bucket (64 nodes each)
#define NFB (NB1 * NSB)  // 3136 fine buckets (3125 non-empty)
#define CHUNK 4096
#define NCH 1563     // 1563*4096 = 6,402,048 >= 6.4M
#define NGRP 25
#define CPG 63       // 25*63 = 1575 >= 1563
#define SCAP 3072    // max edges per 64-node fine bucket
#define NBLK32 (N_NODES / 32)

// ---------- non-temporal helpers ----------
typedef float vf4 __attribute__((ext_vector_type(4)));
typedef float vf2 __attribute__((ext_vector_type(2)));
typedef unsigned vu2 __attribute__((ext_vector_type(2)));

__device__ __forceinline__ unsigned ntload_u(const unsigned* p) {
  return __builtin_nontemporal_load(p);
}
__device__ __forceinline__ int ntload_i(const int* p) { return __builtin_nontemporal_load(p); }
__device__ __forceinline__ float ntload_f(const float* p) {
  return __builtin_nontemporal_load(p);
}
__device__ __forceinline__ void ntstore_u(unsigned* p, unsigned v) {
  __builtin_nontemporal_store(v, p);
}

// ---------- partition pass 1: counting sort of edges by dst>>10 (coarse) ----------
__global__ __launch_bounds__(256) void count_kernel(const int* __restrict__ dst,
                                                    unsigned short* __restrict__ H) {
  __shared__ unsigned hist[4][NB1];
  int t = threadIdx.x, w = t >> 6;
  for (int i = t; i < 4 * NB1; i += 256) ((unsigned*)hist)[i] = 0;
  __syncthreads();
  int c = blockIdx.x;
  long e0 = (long)c * CHUNK;
  long rem = (long)N_EDGES - e0;
  int n = rem > CHUNK ? CHUNK : (int)rem;
  for (int i = t; i < n; i += 256) atomicAdd(&hist[w][dst[e0 + i] >> 10], 1u);
  __syncthreads();
  for (int b = t; b < NB1; b += 256)
    H[(size_t)c * NB1 + b] =
        (unsigned short)(hist[0][b] + hist[1][b] + hist[2][b] + hist[3][b]);
}

__global__ __launch_bounds__(256) void scan_bins1_kernel(unsigned short* __restrict__ H,
                                                         unsigned* __restrict__ P) {
  int b = blockIdx.x * 256 + threadIdx.x;
  int g = blockIdx.y;
  if (b >= NB1) return;
  int c0 = g * CPG, c1 = min(NCH, (g + 1) * CPG);
  unsigned run = 0;
  for (int c = c0; c < c1; c++) {
    unsigned t = H[(size_t)c * NB1 + b];
    H[(size_t)c * NB1 + b] = (unsigned short)run;
    run += t;
  }
  P[(size_t)g * NB1 + b] = run;
}

__global__ __launch_bounds__(256) void scan_bins2_kernel(unsigned* __restrict__ P,
                                                         unsigned* __restrict__ bucketTotal) {
  int b = blockIdx.x * 256 + threadIdx.x;
  if (b >= NB1) return;
  unsigned run = 0;
  for (int g = 0; g < NGRP; g++) {
    unsigned t = P[(size_t)g * NB1 + b];
    P[(size_t)g * NB1 + b] = run;
    run += t;
  }
  bucketTotal[b] = run;
}

__global__ __launch_bounds__(256) void scan_total_kernel(const unsigned* __restrict__ bucketTotal,
                                                         unsigned* __restrict__ bucketStart) {
  __shared__ unsigned partial[256];
  int t = threadIdx.x;
  unsigned v = (t < NB1) ? bucketTotal[t] : 0u;
  partial[t] = v;
  __syncthreads();
  for (int off = 1; off < 256; off <<= 1) {
    unsigned add = (t >= off) ? partial[t - off] : 0u;
    __syncthreads();
    partial[t] += add;
    __syncthreads();
  }
  if (t < NB1) bucketStart[t] = partial[t] - v;  // exclusive
  if (t == 0) bucketStart[NB1] = N_EDGES;
}

// scatterA: chunk-local LDS counting sort by coarse bucket, coalesced-run writes
// X1 entry = (src<<10)|(dst&1023)
__global__ __launch_bounds__(256) void scatterA_kernel(
    const int* __restrict__ src, const int* __restrict__ dst,
    const unsigned short* __restrict__ H, const unsigned* __restrict__ P,
    const unsigned* __restrict__ bucketStart, unsigned* __restrict__ X1) {
  __shared__ unsigned ssort[CHUNK];        // 16 KB (CHUNK=4096)
  __shared__ unsigned char sbort[CHUNK];   // 4 KB
  __shared__ unsigned histw[4][NB1];
  __shared__ unsigned curw[4][NB1];
  __shared__ unsigned gbase[NB1];
  __shared__ unsigned partial[256];
  int t = threadIdx.x, w = t >> 6;
  int c = blockIdx.x;
  int g = c / CPG;
  long e0 = (long)c * CHUNK;
  long rem = (long)N_EDGES - e0;
  int n = rem > CHUNK ? CHUNK : (int)rem;
  for (int i = t; i < 4 * NB1; i += 256) ((unsigned*)histw)[i] = 0;
  __syncthreads();
  for (int i = t; i < n; i += 256) atomicAdd(&histw[w][dst[e0 + i] >> 10], 1u);
  __syncthreads();
  unsigned tot = 0, h0 = 0, h1 = 0, h2 = 0, h3 = 0;
  if (t < NB1) {
    h0 = histw[0][t]; h1 = histw[1][t]; h2 = histw[2][t]; h3 = histw[3][t];
    tot = h0 + h1 + h2 + h3;
  }
  partial[t] = tot;
  __syncthreads();
  for (int off = 1; off < 256; off <<= 1) {
    unsigned add = (t >= off) ? partial[t - off] : 0u;
    __syncthreads();
    partial[t] += add;
    __syncthreads();
  }
  if (t < NB1) {
    unsigned ex = partial[t] - tot;
    unsigned r = ex;
    curw[0][t] = r; r += h0;
    curw[1][t] = r; r += h1;
    curw[2][t] = r; r += h2;
    curw[3][t] = r;
    gbase[t] = bucketStart[t] + P[(size_t)g * NB1 + t] + (unsigned)H[(size_t)c * NB1 + t] - ex;
  }
  __syncthreads();
  for (int i = t; i < n; i += 256) {
    int d = dst[e0 + i], s = src[e0 + i];
    int b = d >> 10;
    unsigned r = atomicAdd(&curw[w][b], 1u);
    ssort[r] = ((unsigned)s << 10) | (unsigned)(d & 1023);
    sbort[r] = (unsigned char)b;
  }
  __syncthreads();
  for (int j = t; j < n; j += 256) X1[gbase[sbort[j]] + j] = ssort[j];
}

// scatterB: one block per coarse bucket -> 16 sub-buckets of 64 nodes
__global__ __launch_bounds__(1024) void scatterB_kernel(
    const unsigned* __restrict__ X1, const unsigned* __restrict__ bucketStart,
    unsigned* __restrict__ X2, unsigned* __restrict__ fineStart) {
  __shared__ unsigned histw[16][NSB];
  __shared__ unsigned binstart[NSB + 1];
  __shared__ unsigned cur[NSB];
  int t = threadIdx.x, w = t >> 6, b = blockIdx.x;
  unsigned cs0 = bucketStart[b], cs1 = bucketStart[b + 1];
  int n = (int)(cs1 - cs0);
  if (t < 16 * NSB) ((unsigned*)histw)[t] = 0;
  __syncthreads();
  for (int i = t; i < n; i += 1024)
    atomicAdd(&histw[w][(X1[cs0 + i] >> 6) & 15u], 1u);
  __syncthreads();
  if (t == 0) {
    unsigned run = 0;
    for (int k = 0; k < NSB; k++) {
      binstart[k] = run;
      unsigned tot = 0;
      for (int ww = 0; ww < 16; ww++) tot += histw[ww][k];
      run += tot;
    }
    binstart[NSB] = run;
  }
  __syncthreads();
  if (t < NSB) {
    fineStart[b * NSB + t] = cs0 + binstart[t];
    cur[t] = binstart[t];
  }
  if (b == NB1 - 1 && t == 0) fineStart[NFB] = cs1;
  __syncthreads();
  for (int i = t; i < n; i += 1024) {
    unsigned v = X1[cs0 + i];
    unsigned pos = atomicAdd(&cur[(v >> 6) & 15u], 1u);
    X2[cs0 + pos] = v;
  }
}

// sort2 (R9's proven unfused form): one block per 64-node fine bucket;
// 128-bin counting sort, bin = (node_low6 << 1) | (src >= HALFN).
// Emits nodeStart + deltaSplit (uchar; max degree ~70 << 256).
__global__ __launch_bounds__(256) void sort2_kernel(const unsigned* __restrict__ X2,
                                                    const unsigned* __restrict__ fineStart,
                                                    unsigned* __restrict__ packedB,
                                                    unsigned* __restrict__ nodeStart,
                                                    unsigned char* __restrict__ deltaSplit) {
  __shared__ unsigned buf[SCAP];
  __shared__ unsigned buf2[SCAP];
  __shared__ unsigned hist[128], base[128], cur[128];
  int t = threadIdx.x, b = blockIdx.x;
  unsigned s0 = fineStart[b], s1 = fineStart[b + 1];
  int n = (int)(s1 - s0);
  if (t < 128) hist[t] = 0;
  for (int i = t; i < n; i += 256) buf[i] = ntload_u(&X2[s0 + i]);
  __syncthreads();
  for (int i = t; i < n; i += 256) {
    unsigned v = buf[i];
    unsigned bin = ((v & 63u) << 1) | ((v >> 10) >= HALFN ? 1u : 0u);
    atomicAdd(&hist[bin], 1u);
  }
  __syncthreads();
  if (t == 0) {
    unsigned run = 0;
    for (int k = 0; k < 128; k++) {
      unsigned v = hist[k];
      base[k] = run;
      cur[k] = run;
      run += v;
    }
  }
  __syncthreads();
  if (t < 64) {
    int gn = b * 64 + t;
    if (gn <= N_NODES) nodeStart[gn] = s0 + base[2 * t];  // bucket 3125/t=0: sentinel
    if (gn < N_NODES) deltaSplit[gn] = (unsigned char)(base[2 * t + 1] - base[2 * t]);
  }
  for (int i = t; i < n; i += 256) {
    unsigned v = buf[i];
    unsigned bin = ((v & 63u) << 1) | ((v >> 10) >= HALFN ? 1u : 0u);
    unsigned pos = atomicAdd(&cur[bin], 1u);
    buf2[pos] = v >> 10;
  }
  __syncthreads();
  for (int i = t; i < n; i += 256) ntstore_u(&packedB[s0 + i], buf2[i]);
}

// ---------- xpad (fp16, 8B records -> 1.6MB table) ----------
__global__ __launch_bounds__(256) void xpad_kernel(const float* __restrict__ x,
                                                   uint2* __restrict__ xph) {
  int n = blockIdx.x * 256 + threadIdx.x;
  if (n >= N_NODES) return;
  __half2 a = __floats2half2_rn(x[3 * n], x[3 * n + 1]);
  __half2 b = __floats2half2_rn(x[3 * n + 2], 0.f);
  xph[n] = make_uint2(*(unsigned*)&a, *(unsigned*)&b);
}

__device__ __forceinline__ void half8_unpack(uint4 g, float* f) {
  const __half2* h2 = reinterpret_cast<const __half2*>(&g);
#pragma unroll
  for (int j = 0; j < 4; j++) {
    float2 fj = __half22float2(h2[j]);
    f[2 * j] = fj.x;
    f[2 * j + 1] = fj.y;
  }
}

// ---------- layer 1a: gather-only, 8 thr/node, fp16 x-table (1.6MB) ----------
__global__ __launch_bounds__(256) void layer1a_kernel(
    const unsigned* __restrict__ packed, const unsigned* __restrict__ nodeStart,
    const uint2* __restrict__ xph, float* __restrict__ agg) {
  __shared__ float plds[256 * 9];
  int t = threadIdx.x, ln = t >> 3, p = t & 7;
  int node = blockIdx.x * 32 + ln;
  unsigned s1v = ntload_u(&nodeStart[node + 1]);
  float a0 = 0.f, a1 = 0.f, a2 = 0.f;
  for (unsigned base = ntload_u(&nodeStart[node]) + p; base < s1v; base += 32) {
    unsigned i1 = base + 8, i2 = base + 16, i3 = base + 24;
    unsigned e0 = ntload_u(&packed[base]);
    unsigned e1 = ntload_u(&packed[i1]);
    unsigned e2 = ntload_u(&packed[i2]);
    unsigned e3 = ntload_u(&packed[i3]);
    uint2 g0 = xph[e0], g1 = xph[e1], g2 = xph[e2], g3 = xph[e3];
    float m1 = (i1 < s1v) ? 1.f : 0.f;
    float m2 = (i2 < s1v) ? 1.f : 0.f;
    float m3 = (i3 < s1v) ? 1.f : 0.f;
    float2 xy0 = __half22float2(*(const __half2*)&g0.x);
    float2 zw0 = __half22float2(*(const __half2*)&g0.y);
    float2 xy1 = __half22float2(*(const __half2*)&g1.x);
    float2 zw1 = __half22float2(*(const __half2*)&g1.y);
    float2 xy2 = __half22float2(*(const __half2*)&g2.x);
    float2 zw2 = __half22float2(*(const __half2*)&g2.y);
    float2 xy3 = __half22float2(*(const __half2*)&g3.x);
    float2 zw3 = __half22float2(*(const __half2*)&g3.y);
    a0 += xy0.x + m1 * xy1.x + m2 * xy2.x + m3 * xy3.x;
    a1 += xy0.y + m1 * xy1.y + m2 * xy2.y + m3 * xy3.y;
    a2 += zw0.x + m1 * zw1.x + m2 * zw2.x + m3 * zw3.x;
  }
  plds[t * 9] = a0; plds[t * 9 + 1] = a1; plds[t * 9 + 2] = a2;
  __syncthreads();
  if (p < 4) {
    int q0 = ln * 72 + p;
    float v = 0.f;
    if (p < 3)
      v = plds[q0] + plds[q0 + 9] + plds[q0 + 18] + plds[q0 + 27] +
          plds[q0 + 36] + plds[q0 + 45] + plds[q0 + 54] + plds[q0 + 63];
    agg[(size_t)node * 4 + p] = v;
  }
}

// ---------- layer 1b: dense-only. Reads x + agg; writes t2h (32B interleaved
// fp16) and r2h (16 feats fp16).
__global__ __launch_bounds__(256) void layer1b_kernel(
    const float* __restrict__ x, const float4* __restrict__ agg,
    const float* __restrict__ W1_rel, const float* __restrict__ b1,
    const float* __restrict__ W1_root,
    const float* __restrict__ W2_rel, const float* __restrict__ W2_root,
    uint4* __restrict__ t2h4, uint4* __restrict__ r2h4) {
  __shared__ float sW1rel[96], sW1root[96], sb1[32], sW2rel[512], sW2root[512];
  for (int i = threadIdx.x; i < 96; i += 256) { sW1rel[i] = W1_rel[i]; sW1root[i] = W1_root[i]; }
  for (int i = threadIdx.x; i < 32; i += 256) sb1[i] = b1[i];
  for (int i = threadIdx.x; i < 512; i += 256) { sW2rel[i] = W2_rel[i]; sW2root[i] = W2_root[i]; }
  __syncthreads();
  int node = blockIdx.x * 256 + threadIdx.x;
  if (node >= N_NODES) return;
  float4 A = agg[node];
  float xv0 = x[3 * node], xv1 = x[3 * node + 1], xv2 = x[3 * node + 2];
  float h[32];
#pragma unroll
  for (int k = 0; k < 32; k++) {
    float v = sW1rel[3 * k] * A.x + sW1rel[3 * k + 1] * A.y + sW1rel[3 * k + 2] * A.z +
              sW1root[3 * k] * xv0 + sW1root[3 * k + 1] * xv1 + sW1root[3 * k + 2] * xv2 +
              sb1[k];
    h[k] = fmaxf(v, 0.f);
  }
  unsigned tp[8];
#pragma unroll
  for (int j = 0; j < 16; j += 2) {
    float t0 = 0.f, t1 = 0.f;
#pragma unroll
    for (int k = 0; k < 32; k++) {
      t0 += sW2rel[32 * j + k] * h[k];
      t1 += sW2rel[32 * (j + 1) + k] * h[k];
    }
    __half2 pk = __halves2half2(__float2half_rn(t0), __float2half_rn(t1));
    tp[j >> 1] = *(unsigned*)&pk;
  }
  t2h4[(size_t)node * 2] = make_uint4(tp[0], tp[1], tp[2], tp[3]);
  t2h4[(size_t)node * 2 + 1] = make_uint4(tp[4], tp[5], tp[6], tp[7]);
  unsigned rp[8];
#pragma unroll
  for (int j = 0; j < 16; j += 2) {
    float r0 = 0.f, r1 = 0.f;
#pragma unroll
    for (int k = 0; k < 32; k++) {
      r0 += sW2root[32 * j + k] * h[k];
      r1 += sW2root[32 * (j + 1) + k] * h[k];
    }
    __half2 pk = __halves2half2(__float2half_rn(r0), __float2half_rn(r1));
    rp[j >> 1] = *(unsigned*)&pk;
  }
  r2h4[(size_t)node * 2] = make_uint4(rp[0], rp[1], rp[2], rp[3]);
  r2h4[(size_t)node * 2 + 1] = make_uint4(rp[4], rp[5], rp[6], rp[7]);
}

// ---------- layer 2g: SRC-RANGE split passes (R9-proven) ----------
__global__ __launch_bounds__(256) void layer2g_kernel(
    const unsigned* __restrict__ packed, const unsigned* __restrict__ nodeStart,
    const unsigned char* __restrict__ deltaSplit,
    const uint4* __restrict__ t2h4, __half* __restrict__ agg2, int pass) {
  __shared__ float plds[256 * 17];
  int t = threadIdx.x, ln = t >> 3, p = t & 7;
  int node = blockIdx.x * 32 + ln;
  unsigned s0n = ntload_u(&nodeStart[node]);
  unsigned s1n = ntload_u(&nodeStart[node + 1]);
  unsigned split = s0n + (unsigned)deltaSplit[node];
  unsigned lo = pass ? split : s0n;
  unsigned hi = pass ? s1n : split;
  float acc[16];
#pragma unroll
  for (int j = 0; j < 16; j++) acc[j] = 0.f;
  for (unsigned base = lo + p; base < hi; base += 16) {
    unsigned i1 = base + 8;
    unsigned e0 = ntload_u(&packed[base]);
    unsigned e1r = ntload_u(&packed[i1]);
    bool in1 = i1 < hi;
    unsigned e1 = in1 ? e1r : e0;  // clamp masked slot to e0's (hot) line
    uint4 g0a = t2h4[(size_t)e0 * 2], g0b = t2h4[(size_t)e0 * 2 + 1];
    uint4 g1a = t2h4[(size_t)e1 * 2], g1b = t2h4[(size_t)e1 * 2 + 1];
    float f0[16], f1[16];
    half8_unpack(g0a, f0);
    half8_unpack(g0b, f0 + 8);
    half8_unpack(g1a, f1);
    half8_unpack(g1b, f1 + 8);
    float m1 = in1 ? 1.f : 0.f;
#pragma unroll
    for (int j = 0; j < 16; j++) acc[j] += f0[j] + m1 * f1[j];
  }
#pragma unroll
  for (int j = 0; j < 16; j++) plds[t * 17 + j] = acc[j];
  __syncthreads();
  int qb = ln * 8 * 17;
  float s0 = 0.f, s1 = 0.f;
#pragma unroll
  for (int k = 0; k < 8; k++) {
    s0 += plds[qb + k * 17 + 2 * p];
    s1 += plds[qb + k * 17 + 2 * p + 1];
  }
  __half* dst = &agg2[(size_t)node * 16 + 2 * p];
  if (pass) {
    __half2 old = *(const __half2*)dst;
    float2 of = __half22float2(old);
    s0 += of.x;
    s1 += of.y;
  }
  *(__half2*)dst = __halves2half2(__float2half_rn(s0), __float2half_rn(s1));
}

// ---------- layer 2e: dense epilogue, 1 thr/node. r3 IN-PLACE over agg2 ----------
__global__ __launch_bounds__(256) void layer2e_kernel(
    const uint4* agg2q, const uint4* __restrict__ r2h4,
    const float* __restrict__ b2, const float* __restrict__ W3_rel,
    const float* __restrict__ W3_root, uint4* __restrict__ t3h4, float4* r34) {
  __shared__ float sW3rel[128], sW3root[128], sb2[16];
  for (int i = threadIdx.x; i < 128; i += 256) { sW3rel[i] = W3_rel[i]; sW3root[i] = W3_root[i]; }
  if (threadIdx.x < 16) sb2[threadIdx.x] = b2[threadIdx.x];
  __syncthreads();
  int node = blockIdx.x * 256 + threadIdx.x;
  if (node >= N_NODES) return;
  uint4 ga = agg2q[(size_t)node * 2];
  uint4 gb = agg2q[(size_t)node * 2 + 1];
  float ag[16];
  half8_unpack(ga, ag);
  half8_unpack(gb, ag + 8);
  uint4 ra = r2h4[(size_t)node * 2];
  uint4 rb = r2h4[(size_t)node * 2 + 1];
  float rv2[16];
  half8_unpack(ra, rv2);
  half8_unpack(rb, rv2 + 8);
  float h[16];
#pragma unroll
  for (int k = 0; k < 16; k++) h[k] = fmaxf(ag[k] + rv2[k] + sb2[k], 0.f);
  unsigned tp[4];
#pragma unroll
  for (int j = 0; j < 8; j += 2) {
    float t0 = 0.f, t1 = 0.f;
#pragma unroll
    for (int k = 0; k < 16; k++) {
      t0 += sW3rel[16 * j + k] * h[k];
      t1 += sW3rel[16 * (j + 1) + k] * h[k];
    }
    __half2 pk = __halves2half2(__float2half_rn(t0), __float2half_rn(t1));
    tp[j >> 1] = *(unsigned*)&pk;
  }
  t3h4[node] = make_uint4(tp[0], tp[1], tp[2], tp[3]);
  float rv[8];
#pragma unroll
  for (int j = 0; j < 8; j++) {
    float a = 0.f;
#pragma unroll
    for (int k = 0; k < 16; k++) a += sW3root[16 * j + k] * h[k];
    rv[j] = a;
  }
  r34[(size_t)node * 2] = make_float4(rv[0], rv[1], rv[2], rv[3]);
  r34[(size_t)node * 2 + 1] = make_float4(rv[4], rv[5], rv[6], rv[7]);
}

// ---------- layer 3: 8 thr/node + block-level segmented-max before atomicMax ----------
__global__ __launch_bounds__(256) void layer3_kernel(
    const unsigned* __restrict__ packed, const unsigned* __restrict__ nodeStart,
    const uint4* __restrict__ t3h4, const float* __restrict__ r3,
    const float* __restrict__ b3,
    const int* __restrict__ batch, unsigned* __restrict__ pooled) {
  __shared__ float plds[256 * 9];
  __shared__ float sb3[8];
  __shared__ int sgid[32];
  if (threadIdx.x < 8) sb3[threadIdx.x] = b3[threadIdx.x];
  __syncthreads();
  int t = threadIdx.x, ln = t >> 3, p = t & 7;
  int node = blockIdx.x * 32 + ln;
  unsigned s1v = ntload_u(&nodeStart[node + 1]);
  float acc[8];
#pragma unroll
  for (int j = 0; j < 8; j++) acc[j] = 0.f;
  for (unsigned base = ntload_u(&nodeStart[node]) + p; base < s1v; base += 32) {
    unsigned i1 = base + 8, i2 = base + 16, i3 = base + 24;
    unsigned e0 = ntload_u(&packed[base]);
    unsigned e1 = ntload_u(&packed[i1]);
    unsigned e2 = ntload_u(&packed[i2]);
    unsigned e3 = ntload_u(&packed[i3]);
    uint4 g0 = t3h4[e0];
    uint4 g1 = t3h4[e1];
    uint4 g2 = t3h4[e2];
    uint4 g3 = t3h4[e3];
    float m1 = (i1 < s1v) ? 1.f : 0.f;
    float m2 = (i2 < s1v) ? 1.f : 0.f;
    float m3 = (i3 < s1v) ? 1.f : 0.f;
    float f0[8], f1[8], f2[8], f3[8];
    half8_unpack(g0, f0);
    half8_unpack(g1, f1);
    half8_unpack(g2, f2);
    half8_unpack(g3, f3);
#pragma unroll
    for (int j = 0; j < 8; j++)
      acc[j] += f0[j] + m1 * f1[j] + m2 * f2[j] + m3 * f3[j];
  }
#pragma unroll
  for (int j = 0; j < 8; j++) plds[t * 9 + j] = acc[j];
  __syncthreads();
  int gg = ntload_i(&batch[node]);
  int q0 = ln * 72 + p;
  float v = plds[q0] + plds[q0 + 9] + plds[q0 + 18] + plds[q0 + 27] +
            plds[q0 + 36] + plds[q0 + 45] + plds[q0 + 54] + plds[q0 + 63];
  float h = fmaxf(v + sb3[p] + ntload_f(&r3[(size_t)node * 8 + p]), 0.f);
  __syncthreads();
  plds[ln * 9 + p] = h;
  if (p == 0) sgid[ln] = gg;
  __syncthreads();
  if (t < 8) {
    int gcur = sgid[0];
    float m = plds[t];
    for (int l = 1; l < 32; l++) {
      int g2 = sgid[l];
      float hv = plds[l * 9 + t];
      if (g2 != gcur) {
        atomicMax(&pooled[8 * gcur + t], __float_as_uint(m));
        gcur = g2;
        m = hv;
      } else {
        m = fmaxf(m, hv);
      }
    }
    atomicMax(&pooled[8 * gcur + t], __float_as_uint(m));
  }
}

__global__ __launch_bounds__(256) void final_kernel(
    const unsigned* __restrict__ pooled, const float* __restrict__ W_lin,
    const float* __restrict__ b_lin, float* __restrict__ out) {
  int g = blockIdx.x * blockDim.x + threadIdx.x;
  if (g >= N_GRAPHS) return;
  float acc = b_lin[0];
#pragma unroll
  for (int f = 0; f < 8; f++) acc += __uint_as_float(pooled[8 * g + f]) * W_lin[f];
  out[g] = acc;
}

extern "C" void kernel_launch(void* const* d_in, const int* in_sizes, int n_in,
                              void* d_out, int out_size, void* d_ws, size_t ws_size,
                              hipStream_t stream) {
  const float* x = (const float*)d_in[0];
  const int* ei = (const int*)d_in[1];
  const int* src = ei;
  const int* dst = ei + N_EDGES;
  const int* batch = (const int*)d_in[2];
  const float* W1_rel = (const float*)d_in[3];
  const float* b1 = (const float*)d_in[4];
  const float* W1_root = (const float*)d_in[5];
  const float* W2_rel = (const float*)d_in[6];
  const float* b2 = (const float*)d_in[7];
  const float* W2_root = (const float*)d_in[8];
  const float* W3_rel = (const float*)d_in[9];
  const float* b3 = (const float*)d_in[10];
  const float* W3_root = (const float*)d_in[11];
  const float* W_lin = (const float*)d_in[12];
  const float* b_lin = (const float*)d_in[13];
  float* out = (float*)d_out;

  // ---- workspace layout (bytes) — R11's audited layout ----
  // R_A (0..25.6M): X2 (sort2 input). Post-sort2 aliases:
  //   r2h  0..6.4M       (layer1b w / layer2e r)
  //   agg2 6.4..12.8M    (layer2g w/r) -> r3 fp32 in-place (layer2e w, layer3 r)
  //   t3h  12.8..16.0M   (layer2e w, layer3 r)
  //   t2h  16.0..22.4M   (layer1b w, layer2g r)   [22.4..25.6M spare]
  // R_B (25.6..51.2M): X1 -> packedB + 128 pad
  // meta (51.2M+128..): H(612K)/P/totals/starts/fineStart (ends 51.85M),
  //   agg   52.0..55.2M  (layer1a w, layer1b r)
  //   xpadh 55.3..56.9M  (xpad w FIRST, layer1a r)
  // pooled 57.6M; deltaSplit (uchar) 57.616M; nodeStart 57.954M -> 58.754M
  char* ws = (char*)d_ws;
  unsigned* X2 = (unsigned*)(ws + 0);
  uint4* r2h = (uint4*)(ws + 0);
  __half* agg2 = (__half*)(ws + 6400000);
  float* r3 = (float*)(ws + 6400000);
  unsigned* t3h = (unsigned*)(ws + 12800000);
  unsigned* t2h = (unsigned*)(ws + 16000000);
  unsigned* X1 = (unsigned*)(ws + 25600000);
  unsigned* packedB = (unsigned*)(ws + 25600000);
  unsigned short* H = (unsigned short*)(ws + 51200128);
  unsigned* P = (unsigned*)(ws + 51812824);
  unsigned* bucketTotal = (unsigned*)(ws + 51832424);
  unsigned* bucketStart = (unsigned*)(ws + 51833208);
  unsigned* fineStart = (unsigned*)(ws + 51833996);      // ends 51,846,544
  float* agg = (float*)(ws + 52000000);                  // 3,200,000 -> 55.2M
  uint2* xpadh = (uint2*)(ws + 55300000);                // 1,600,000 -> 56.9M
  unsigned* pooled = (unsigned*)(ws + 57600128);
  unsigned char* deltaSplit = (unsigned char*)(ws + 57616512);  // 200,000
  unsigned* nodeStart = (unsigned*)(ws + 57954016);      // 800,004 -> 58,754,020

  hipMemsetAsync(pooled, 0, N_GRAPHS * 8 * sizeof(unsigned), stream);
  hipMemsetAsync(packedB + N_EDGES, 0, 128, stream);  // batch overrun pad (src=0 safe)

  // xpadh first: independent of partition, needed by layer1a
  xpad_kernel<<<(N_NODES + 255) / 256, 256, 0, stream>>>(x, xpadh);

  // partition: coarse sort (196 buckets) -> 16-way fine split -> node sort
  count_kernel<<<NCH, 256, 0, stream>>>(dst, H);
  scan_bins1_kernel<<<dim3((NB1 + 255) / 256, NGRP), 256, 0, stream>>>(H, P);
  scan_bins2_kernel<<<(NB1 + 255) / 256, 256, 0, stream>>>(P, bucketTotal);
  scan_total_kernel<<<1, 256, 0, stream>>>(bucketTotal, bucketStart);
  scatterA_kernel<<<NCH, 256, 0, stream>>>(src, dst, H, P, bucketStart, X1);
  scatterB_kernel<<<NB1, 1024, 0, stream>>>(X1, bucketStart, X2, fineStart);
  sort2_kernel<<<NFB, 256, 0, stream>>>(X2, fineStart, packedB, nodeStart, deltaSplit);

  // layer1: gather (fp16 table) + dense epilogue
  layer1a_kernel<<<NBLK32, 256, 0, stream>>>(packedB, nodeStart, xpadh, agg);
  layer1b_kernel<<<(N_NODES + 255) / 256, 256, 0, stream>>>(
      x, (const float4*)agg, W1_rel, b1, W1_root, W2_rel, W2_root,
      (uint4*)t2h, r2h);

  // layer2: two src-range passes + dense epilogue
  layer2g_kernel<<<NBLK32, 256, 0, stream>>>(packedB, nodeStart, deltaSplit,
                                             (const uint4*)t2h, agg2, 0);
  layer2g_kernel<<<NBLK32, 256, 0, stream>>>(packedB, nodeStart, deltaSplit,
                                             (const uint4*)t2h, agg2, 1);
  layer2e_kernel<<<(N_NODES + 255) / 256, 256, 0, stream>>>(
      (const uint4*)agg2, (const uint4*)r2h, b2, W3_rel, W3_root,
      (uint4*)t3h, (float4*)r3);

  layer3_kernel<<<NBLK32, 256, 0, stream>>>(packedB, nodeStart, (const uint4*)t3h, r3, b3,
                                            batch, pooled);
  final_kernel<<<(N_GRAPHS + 255) / 256, 256, 0, stream>>>(pooled, W_lin, b_lin, out);
}